// Round 2
// baseline (262.637 us; speedup 1.0000x reference)
//
#include <hip/hip_runtime.h>
#include <hip/hip_fp16.h>
#include <hip/hip_cooperative_groups.h>

namespace cg = cooperative_groups;

#define N_POINTS   100000
#define N_EVENTS   1000000
#define N_PAIRS    100000
#define N_RIEMANN  128
#define EPS_F      1e-6f
#define NON_EVENT_W 1.0f

constexpr int BLOCK = 256;

// ---- event side: 8 contiguous events per thread (16 gathers in flight) ----
constexpr int EVPT       = 8;
constexpr int EV_THREADS = N_EVENTS / EVPT;                      // 125000 (exact)
constexpr int EV_BLOCKS  = (EV_THREADS + BLOCK - 1) / BLOCK;     // 489

// ---- pair side: each pair split across 4 threads, 32 Riemann steps each ----
constexpr int RPT          = 32;
constexpr int CHUNKS       = N_RIEMANN / RPT;                    // 4
constexpr int PAIR_THREADS = N_PAIRS * CHUNKS;                   // 400000
constexpr int PAIR_BLOCKS  = (PAIR_THREADS + BLOCK - 1) / BLOCK; // 1563

// Virtual-block space: EVENTS FIRST so every CU hosts a mix of
// gather-latency blocks and VALU blocks from t=0 (latency hiding via TLP).
constexpr int VB_TOTAL = EV_BLOCKS + PAIR_BLOCKS;                // 2052

// Packed point record (16 B): half2 z | half2 v | half2 a | pad.
// One dwordx4 gather per point; 4 points per 64 B line; table = 1.6 MB (L2-resident).

__device__ __forceinline__ float block_reduce_sum(float v) {
    #pragma unroll
    for (int off = 32; off > 0; off >>= 1)
        v += __shfl_down(v, off, 64);
    __shared__ float smem[BLOCK / 64];
    const int lane = threadIdx.x & 63;
    const int wid  = threadIdx.x >> 6;
    if (lane == 0) smem[wid] = v;
    __syncthreads();
    float r = 0.f;
    if (threadIdx.x == 0) {
        #pragma unroll
        for (int i = 0; i < BLOCK / 64; ++i) r += smem[i];
    }
    return r;
}

__device__ __forceinline__ void decode_rec(const float4& r, float2& z, float2& v, float2& a) {
    z = __half22float2(*reinterpret_cast<const __half2*>(&r.x));
    v = __half22float2(*reinterpret_cast<const __half2*>(&r.y));
    a = __half22float2(*reinterpret_cast<const __half2*>(&r.z));
}

template <bool PACKED>
__global__ __launch_bounds__(BLOCK) void fused_kernel(
    float4*       __restrict__ pts,
    const float2* __restrict__ z0,
    const float2* __restrict__ v0,
    const float2* __restrict__ a0,
    const float*  __restrict__ beta,
    const int*    __restrict__ eu,
    const int*    __restrict__ ev,
    const float*  __restrict__ et,
    const int*    __restrict__ pu,
    const int*    __restrict__ pv,
    const float*  __restrict__ t0p,
    const float*  __restrict__ tnp,
    float*        __restrict__ partials,
    float*        __restrict__ out)
{
    const int G = gridDim.x;

    // ---- phase A: pack fp16 point table (replaces prep dispatch) ----
    if constexpr (PACKED) {
        for (int i = blockIdx.x * BLOCK + threadIdx.x; i < N_POINTS; i += G * BLOCK) {
            const float2 z = z0[i], v = v0[i], a = a0[i];
            float4 r;
            *reinterpret_cast<__half2*>(&r.x) = __float22half2_rn(make_float2(z.x, z.y));
            *reinterpret_cast<__half2*>(&r.y) = __float22half2_rn(make_float2(v.x, v.y));
            *reinterpret_cast<__half2*>(&r.z) = __float22half2_rn(make_float2(a.x, a.y));
            r.w = 0.f;
            pts[i] = r;
        }
        cg::this_grid().sync();
    }

    const float t0v  = t0p[0];
    const float tnv  = tnp[0];
    const float bb   = beta[0];
    const float step = (tnv - t0v) * (1.0f / N_RIEMANN);   // == dt
    const float neg_dt_eb = -NON_EVENT_W * step * __expf(bb);

    float acc = 0.f;

    // ---- phase B: virtual blocks, events first ----
    for (int vb = blockIdx.x; vb < VB_TOTAL; vb += G) {
        if (vb < EV_BLOCKS) {
            // ---- event term: 8 contiguous events/thread; 16 gathers in flight ----
            const int t = vb * BLOCK + threadIdx.x;
            if (t < EV_THREADS) {
                const int4*   eu4 = reinterpret_cast<const int4*>(eu);
                const int4*   ev4 = reinterpret_cast<const int4*>(ev);
                const float4* et4 = reinterpret_cast<const float4*>(et);
                const int4 u0 = eu4[2 * t], u1 = eu4[2 * t + 1];
                const int4 w0 = ev4[2 * t], w1 = ev4[2 * t + 1];
                const float4 t0q = et4[2 * t], t1q = et4[2 * t + 1];
                const int iu[EVPT] = { u0.x, u0.y, u0.z, u0.w, u1.x, u1.y, u1.z, u1.w };
                const int iv[EVPT] = { w0.x, w0.y, w0.z, w0.w, w1.x, w1.y, w1.z, w1.w };
                const float te[EVPT] = { t0q.x, t0q.y, t0q.z, t0q.w, t1q.x, t1q.y, t1q.z, t1q.w };
                if constexpr (PACKED) {
                    float4 ru[EVPT], rv[EVPT];
                    #pragma unroll
                    for (int j = 0; j < EVPT; ++j) ru[j] = pts[iu[j]];
                    #pragma unroll
                    for (int j = 0; j < EVPT; ++j) rv[j] = pts[iv[j]];
                    #pragma unroll
                    for (int j = 0; j < EVPT; ++j) {
                        float2 zu, vu, au, zv, vv, av;
                        decode_rec(ru[j], zu, vu, au);
                        decode_rec(rv[j], zv, vv, av);
                        const float h = 0.5f * te[j] * te[j];
                        const float dx = (zu.x - zv.x) + (vu.x - vv.x) * te[j] + (au.x - av.x) * h + EPS_F;
                        const float dy = (zu.y - zv.y) + (vu.y - vv.y) * te[j] + (au.y - av.y) * h + EPS_F;
                        acc -= __builtin_amdgcn_sqrtf(__fmaf_rn(dy, dy, dx * dx));
                    }
                } else {
                    #pragma unroll
                    for (int j = 0; j < EVPT; ++j) {
                        const float2 zu = z0[iu[j]], zv = z0[iv[j]];
                        const float2 vu = v0[iu[j]], vv = v0[iv[j]];
                        const float2 au = a0[iu[j]], av = a0[iv[j]];
                        const float h = 0.5f * te[j] * te[j];
                        const float dx = (zu.x - zv.x) + (vu.x - vv.x) * te[j] + (au.x - av.x) * h + EPS_F;
                        const float dy = (zu.y - zv.y) + (vu.y - vv.y) * te[j] + (au.y - av.y) * h + EPS_F;
                        acc -= __builtin_amdgcn_sqrtf(__fmaf_rn(dy, dy, dx * dx));
                    }
                }
            }
        } else {
            // ---- non-event term: 4 threads per pair, 32 Riemann steps each ----
            const int p = (vb - EV_BLOCKS) * BLOCK + threadIdx.x;
            if (p < PAIR_THREADS) {
                const int chunk = p / N_PAIRS;               // 0..3 (magic-mul)
                const int pr    = p - chunk * N_PAIRS;
                const int iu = pu[pr];
                const int iv = pv[pr];
                float dzx, dzy, dvx, dvy, dax, day;
                if constexpr (PACKED) {
                    const float4 ru = pts[iu];
                    const float4 rv = pts[iv];
                    float2 zu, vu, au, zv, vv, av;
                    decode_rec(ru, zu, vu, au);
                    decode_rec(rv, zv, vv, av);
                    dzx = zu.x - zv.x; dzy = zu.y - zv.y;
                    dvx = vu.x - vv.x; dvy = vu.y - vv.y;
                    dax = au.x - av.x; day = au.y - av.y;
                } else {
                    const float2 zu = z0[iu], zv = z0[iv];
                    const float2 vu = v0[iu], vv = v0[iv];
                    const float2 au = a0[iu], av = a0[iv];
                    dzx = zu.x - zv.x; dzy = zu.y - zv.y;
                    dvx = vu.x - vv.x; dvy = vu.y - vv.y;
                    dax = au.x - av.x; day = au.y - av.y;
                }
                const float dzxe = dzx + EPS_F;
                const float dzye = dzy + EPS_F;
                const float hax  = 0.5f * dax;
                const float hay  = 0.5f * day;
                float s = 0.f;
                const int k0 = chunk * RPT;
                #pragma unroll 8
                for (int k = k0; k < k0 + RPT; ++k) {
                    const float t  = __fmaf_rn((float)k, step, t0v);
                    const float h  = t * t;                    // 0.5 folded into hax/hay
                    const float dx = __fmaf_rn(hax, h, __fmaf_rn(dvx, t, dzxe));
                    const float dy = __fmaf_rn(hay, h, __fmaf_rn(dvy, t, dzye));
                    const float d  = __builtin_amdgcn_sqrtf(__fmaf_rn(dy, dy, dx * dx));
                    s += __expf(-d);
                }
                acc += neg_dt_eb * s;
            }
        }
    }

    // ---- per-block reduce, then grid-wide final reduce (replaces reduce dispatch) ----
    const float r = block_reduce_sum(acc);
    if (threadIdx.x == 0) partials[blockIdx.x] = r;
    cg::this_grid().sync();

    if (blockIdx.x == 0) {
        float a2 = 0.f;
        for (int i = threadIdx.x; i < G; i += BLOCK) a2 += partials[i];
        const float rr = block_reduce_sum(a2);
        if (threadIdx.x == 0) out[0] = bb * (float)N_EVENTS + rr;
    }
}

extern "C" void kernel_launch(void* const* d_in, const int* in_sizes, int n_in,
                              void* d_out, int out_size, void* d_ws, size_t ws_size,
                              hipStream_t stream) {
    const float*  beta = (const float*)d_in[0];
    const float2* z0   = (const float2*)d_in[1];
    const float2* v0   = (const float2*)d_in[2];
    const float2* a0   = (const float2*)d_in[3];
    const int*    eu   = (const int*)d_in[4];
    const int*    ev   = (const int*)d_in[5];
    const float*  et   = (const float*)d_in[6];
    const int*    pu   = (const int*)d_in[7];
    const int*    pv   = (const int*)d_in[8];
    const float*  t0p  = (const float*)d_in[9];
    const float*  tnp  = (const float*)d_in[10];

    float* out = (float*)d_out;
    const size_t pts_bytes = (size_t)N_POINTS * sizeof(float4);

    // Co-residency-legal grid for cooperative launch (cached; host-only, capture-safe).
    static int grid_packed = 0, grid_plain = 0;
    if (grid_packed == 0) {
        int nb = 0;
        if (hipOccupancyMaxActiveBlocksPerMultiprocessor(&nb, fused_kernel<true>, BLOCK, 0) != hipSuccess || nb < 1) nb = 2;
        grid_packed = nb * 256;                       // 256 CUs on MI355X
        if (grid_packed > VB_TOTAL) grid_packed = VB_TOTAL;
        nb = 0;
        if (hipOccupancyMaxActiveBlocksPerMultiprocessor(&nb, fused_kernel<false>, BLOCK, 0) != hipSuccess || nb < 1) nb = 2;
        grid_plain = nb * 256;
        if (grid_plain > VB_TOTAL) grid_plain = VB_TOTAL;
    }

    const bool packed = (ws_size >= pts_bytes + (size_t)VB_TOTAL * sizeof(float));
    float4* pts      = packed ? (float4*)d_ws : nullptr;
    float*  partials = packed ? (float*)((char*)d_ws + pts_bytes) : (float*)d_ws;

    void* args[] = { &pts, &z0, &v0, &a0, &beta, &eu, &ev, &et,
                     &pu, &pv, &t0p, &tnp, &partials, &out };

    if (packed) {
        hipLaunchCooperativeKernel(fused_kernel<true>,  dim3(grid_packed), dim3(BLOCK), args, 0, stream);
    } else {
        hipLaunchCooperativeKernel(fused_kernel<false>, dim3(grid_plain),  dim3(BLOCK), args, 0, stream);
    }
}

// Round 3
// 104.214 us; speedup vs baseline: 2.5202x; 2.5202x over previous
//
#include <hip/hip_runtime.h>
#include <hip/hip_fp16.h>

#define N_POINTS   100000
#define N_EVENTS   1000000
#define N_PAIRS    100000
#define N_RIEMANN  128
#define EPS_F      1e-6f
#define NON_EVENT_W 1.0f

constexpr int BLOCK = 256;

// ---- event side: 2 events/thread -> 500k threads, latency hidden by TLP not ILP ----
constexpr int EVPT       = 2;
constexpr int EV_THREADS = N_EVENTS / EVPT;                      // 500000 (exact)
constexpr int EV_BLOCKS  = (EV_THREADS + BLOCK - 1) / BLOCK;     // 1954

// ---- pair side: each pair split across 4 threads, 32 Riemann steps each ----
constexpr int RPT          = 32;
constexpr int CHUNKS       = N_RIEMANN / RPT;                    // 4
constexpr int PAIR_THREADS = N_PAIRS * CHUNKS;                   // 400000
constexpr int PAIR_BLOCKS  = (PAIR_THREADS + BLOCK - 1) / BLOCK; // 1563

// Virtual-block space with Bresenham interleave: every CU hosts a mix of
// gather-latency (event) and VALU-heavy (pair) blocks throughout the kernel.
constexpr int VB_TOTAL = EV_BLOCKS + PAIR_BLOCKS;                // 3517

constexpr int PREP_BLOCKS = (N_POINTS + BLOCK - 1) / BLOCK;

// Packed point record (16 B): half2 z | half2 v | half2 a | pad.
// One dwordx4 gather per point; 4 points per 64 B line; table = 1.6 MB (L2-resident).

__device__ __forceinline__ float block_reduce_sum(float v) {
    #pragma unroll
    for (int off = 32; off > 0; off >>= 1)
        v += __shfl_down(v, off, 64);
    __shared__ float smem[BLOCK / 64];
    const int lane = threadIdx.x & 63;
    const int wid  = threadIdx.x >> 6;
    if (lane == 0) smem[wid] = v;
    __syncthreads();
    float r = 0.f;
    if (threadIdx.x == 0) {
        #pragma unroll
        for (int i = 0; i < BLOCK / 64; ++i) r += smem[i];
    }
    return r;
}

__device__ __forceinline__ void decode_rec(const float4& r, float2& z, float2& v, float2& a) {
    z = __half22float2(*reinterpret_cast<const __half2*>(&r.x));
    v = __half22float2(*reinterpret_cast<const __half2*>(&r.y));
    a = __half22float2(*reinterpret_cast<const __half2*>(&r.z));
}

__global__ __launch_bounds__(BLOCK) void prep_kernel(
    const float2* __restrict__ z0,
    const float2* __restrict__ v0,
    const float2* __restrict__ a0,
    float4*       __restrict__ pts)
{
    const int i = blockIdx.x * BLOCK + threadIdx.x;
    if (i < N_POINTS) {
        const float2 z = z0[i], v = v0[i], a = a0[i];
        float4 r;
        *reinterpret_cast<__half2*>(&r.x) = __float22half2_rn(make_float2(z.x, z.y));
        *reinterpret_cast<__half2*>(&r.y) = __float22half2_rn(make_float2(v.x, v.y));
        *reinterpret_cast<__half2*>(&r.z) = __float22half2_rn(make_float2(a.x, a.y));
        r.w = 0.f;
        pts[i] = r;
    }
}

template <bool PACKED>
__global__ __launch_bounds__(BLOCK) void main_kernel(
    const float4* __restrict__ pts,
    const float2* __restrict__ z0,
    const float2* __restrict__ v0,
    const float2* __restrict__ a0,
    const float*  __restrict__ beta,
    const int*    __restrict__ eu,
    const int*    __restrict__ ev,
    const float*  __restrict__ et,
    const int*    __restrict__ pu,
    const int*    __restrict__ pv,
    const float*  __restrict__ t0p,
    const float*  __restrict__ tnp,
    float*        __restrict__ partials)
{
    float acc = 0.f;
    const int b = blockIdx.x;

    // Bresenham select: block b is an event block iff floor((b+1)*EV/TOT) > floor(b*EV/TOT).
    // Event index = f0; pair index = b - f0.  Uniform mixing for any ratio.
    const int f0 = (int)(((long long)b       * EV_BLOCKS) / VB_TOTAL);
    const int f1 = (int)(((long long)(b + 1) * EV_BLOCKS) / VB_TOTAL);

    if (f1 > f0) {
        // ---- event term: 2 events/thread; 4 gathers in flight, hidden by TLP ----
        const int t = f0 * BLOCK + threadIdx.x;
        if (t < EV_THREADS) {
            const int2*   eu2 = reinterpret_cast<const int2*>(eu);
            const int2*   ev2 = reinterpret_cast<const int2*>(ev);
            const float2* et2 = reinterpret_cast<const float2*>(et);
            const int2   u  = eu2[t];
            const int2   w  = ev2[t];
            const float2 tq = et2[t];
            if constexpr (PACKED) {
                const float4 ru0 = pts[u.x];
                const float4 rv0 = pts[w.x];
                const float4 ru1 = pts[u.y];
                const float4 rv1 = pts[w.y];
                {
                    float2 zu, vu, au, zv, vv, av;
                    decode_rec(ru0, zu, vu, au);
                    decode_rec(rv0, zv, vv, av);
                    const float h  = 0.5f * tq.x * tq.x;
                    const float dx = (zu.x - zv.x) + (vu.x - vv.x) * tq.x + (au.x - av.x) * h + EPS_F;
                    const float dy = (zu.y - zv.y) + (vu.y - vv.y) * tq.x + (au.y - av.y) * h + EPS_F;
                    acc -= __builtin_amdgcn_sqrtf(__fmaf_rn(dy, dy, dx * dx));
                }
                {
                    float2 zu, vu, au, zv, vv, av;
                    decode_rec(ru1, zu, vu, au);
                    decode_rec(rv1, zv, vv, av);
                    const float h  = 0.5f * tq.y * tq.y;
                    const float dx = (zu.x - zv.x) + (vu.x - vv.x) * tq.y + (au.x - av.x) * h + EPS_F;
                    const float dy = (zu.y - zv.y) + (vu.y - vv.y) * tq.y + (au.y - av.y) * h + EPS_F;
                    acc -= __builtin_amdgcn_sqrtf(__fmaf_rn(dy, dy, dx * dx));
                }
            } else {
                #pragma unroll
                for (int j = 0; j < EVPT; ++j) {
                    const int   iu = (j == 0) ? u.x : u.y;
                    const int   iv = (j == 0) ? w.x : w.y;
                    const float te = (j == 0) ? tq.x : tq.y;
                    const float2 zu = z0[iu], zv = z0[iv];
                    const float2 vu = v0[iu], vv = v0[iv];
                    const float2 au = a0[iu], av = a0[iv];
                    const float h  = 0.5f * te * te;
                    const float dx = (zu.x - zv.x) + (vu.x - vv.x) * te + (au.x - av.x) * h + EPS_F;
                    const float dy = (zu.y - zv.y) + (vu.y - vv.y) * te + (au.y - av.y) * h + EPS_F;
                    acc -= __builtin_amdgcn_sqrtf(__fmaf_rn(dy, dy, dx * dx));
                }
            }
        }
    } else {
        // ---- non-event term: 4 threads per pair, 32 Riemann steps each ----
        const int p = (b - f0) * BLOCK + threadIdx.x;
        if (p < PAIR_THREADS) {
            const int chunk = p / N_PAIRS;               // 0..3 (magic-mul)
            const int pr    = p - chunk * N_PAIRS;
            const float t0v  = t0p[0];
            const float tnv  = tnp[0];
            const float step = (tnv - t0v) * (1.0f / N_RIEMANN);   // == dt
            const float bb   = beta[0];
            const int iu = pu[pr];
            const int iv = pv[pr];
            float dzx, dzy, dvx, dvy, dax, day;
            if constexpr (PACKED) {
                const float4 ru = pts[iu];
                const float4 rv = pts[iv];
                float2 zu, vu, au, zv, vv, av;
                decode_rec(ru, zu, vu, au);
                decode_rec(rv, zv, vv, av);
                dzx = zu.x - zv.x; dzy = zu.y - zv.y;
                dvx = vu.x - vv.x; dvy = vu.y - vv.y;
                dax = au.x - av.x; day = au.y - av.y;
            } else {
                const float2 zu = z0[iu], zv = z0[iv];
                const float2 vu = v0[iu], vv = v0[iv];
                const float2 au = a0[iu], av = a0[iv];
                dzx = zu.x - zv.x; dzy = zu.y - zv.y;
                dvx = vu.x - vv.x; dvy = vu.y - vv.y;
                dax = au.x - av.x; day = au.y - av.y;
            }
            const float dzxe = dzx + EPS_F;
            const float dzye = dzy + EPS_F;
            const float hax  = 0.5f * dax;
            const float hay  = 0.5f * day;
            float s = 0.f;
            const int k0 = chunk * RPT;
            #pragma unroll 8
            for (int k = k0; k < k0 + RPT; ++k) {
                const float t  = __fmaf_rn((float)k, step, t0v);
                const float h  = t * t;                    // 0.5 folded into hax/hay
                const float dx = __fmaf_rn(hax, h, __fmaf_rn(dvx, t, dzxe));
                const float dy = __fmaf_rn(hay, h, __fmaf_rn(dvy, t, dzye));
                const float d  = __builtin_amdgcn_sqrtf(__fmaf_rn(dy, dy, dx * dx));
                s += __expf(-d);
            }
            acc = -NON_EVENT_W * step * __expf(bb) * s;
        }
    }

    const float r = block_reduce_sum(acc);
    if (threadIdx.x == 0) partials[blockIdx.x] = r;   // no atomics — no serialization
}

__global__ __launch_bounds__(BLOCK) void reduce_kernel(
    const float* __restrict__ partials,
    const float* __restrict__ beta,
    float*       __restrict__ out)
{
    float acc = 0.f;
    for (int i = threadIdx.x; i < VB_TOTAL; i += BLOCK) acc += partials[i];
    const float r = block_reduce_sum(acc);
    if (threadIdx.x == 0) out[0] = beta[0] * (float)N_EVENTS + r;
}

extern "C" void kernel_launch(void* const* d_in, const int* in_sizes, int n_in,
                              void* d_out, int out_size, void* d_ws, size_t ws_size,
                              hipStream_t stream) {
    const float*  beta = (const float*)d_in[0];
    const float2* z0   = (const float2*)d_in[1];
    const float2* v0   = (const float2*)d_in[2];
    const float2* a0   = (const float2*)d_in[3];
    const int*    eu   = (const int*)d_in[4];
    const int*    ev   = (const int*)d_in[5];
    const float*  et   = (const float*)d_in[6];
    const int*    pu   = (const int*)d_in[7];
    const int*    pv   = (const int*)d_in[8];
    const float*  t0p  = (const float*)d_in[9];
    const float*  tnp  = (const float*)d_in[10];

    float* out = (float*)d_out;
    const size_t pts_bytes = (size_t)N_POINTS * sizeof(float4);
    const bool packed = (ws_size >= pts_bytes + (size_t)VB_TOTAL * sizeof(float));

    if (packed) {
        float4* pts      = (float4*)d_ws;
        float*  partials = (float*)((char*)d_ws + pts_bytes);
        prep_kernel<<<PREP_BLOCKS, BLOCK, 0, stream>>>(z0, v0, a0, pts);
        main_kernel<true><<<VB_TOTAL, BLOCK, 0, stream>>>(
            pts, z0, v0, a0, beta, eu, ev, et, pu, pv, t0p, tnp, partials);
        reduce_kernel<<<1, BLOCK, 0, stream>>>(partials, beta, out);
    } else {
        float* partials = (float*)d_ws;       // needs only ~14 KB
        main_kernel<false><<<VB_TOTAL, BLOCK, 0, stream>>>(
            nullptr, z0, v0, a0, beta, eu, ev, et, pu, pv, t0p, tnp, partials);
        reduce_kernel<<<1, BLOCK, 0, stream>>>(partials, beta, out);
    }
}